// Round 17
// baseline (8855.541 us; speedup 1.0000x reference)
//
#include <hip/hip_runtime.h>
#include <hip/hip_fp16.h>
#include <math.h>

// betaChessAI forward: 10 blocks of {conv-bn-conv-bn residual, windowed attention, MLP}
// R17 = R16 (8.47ms) + SWAP grid-axis mapping on the K=512 token GEMMs:
//   consecutive blocks share the A tile (L2-hot) and sweep the small weight panels,
//   so the 16.8MB A panel is streamed once per dispatch instead of 4-12x.
// Layouts:
//   spatial activations: act16[(b*64 + p)*128 + c], p = y*8+x   (== feat layout for head)
//   token activations:   t[(b*16 + n)*512 + d],  d = (p1*2+p2)*128 + c, n = hy*4+wx
// Workspace (float slots), ~147 MB.

#define NBATCH 4096
#define NPOSR  (NBATCH*64)
#define CH     1024                    // images per attention chunk
#define CHT    (CH*16)                 // tokens per chunk = 16384

#define OFF_ACT   0                    // act16: 33,554,432 halfs = 16,777,216 f32 slots
#define OFF_BIG2  16777216
#define OFF_WT1   (OFF_BIG2 + 16777216)
#define OFF_WTA   (OFF_WT1 + 13824)    // f16 [10][128][1152] in 737,280 f32 slots
#define OFF_WTB   (OFF_WTA + 737280)
#define OFF_WTT   (OFF_WTB + 737280)   // f16 transformer weights, 1,572,864 halfs
#define OFF_STATS (OFF_WTT + 786432)   // 20 slots x 256 floats
#define OFF_BIAS  (OFF_STATS + 5120)   // scaled qkv bias, 1536 f32
#define WS_NEED_FLOATS (OFF_BIAS + 1536)

// big2 half-offsets (transformer phase, CH=1024):
//   conv phase: z1h = full big2 [0, 33.55M)
//   chunk loop: qkvbuf [0, 25.17M) ; attnout [25.17M, 33.55M) ; t2h [8.39M, 16.78M)
#define H_QKVB 0
#define H_ATT  25165824
#define H_T2H  8388608
#define H_LOG  8388608                 // head phase: logits f32 at halfs [8.39M, 13.63M)

// wTt half-offsets
#define T_QKV  0
#define T_PRJ  786432
#define T_F1   1048576
#define T_F2   1310720

typedef _Float16 f16x8 __attribute__((ext_vector_type(8)));
typedef _Float16 f16x4 __attribute__((ext_vector_type(4)));
typedef float f32x4 __attribute__((ext_vector_type(4)));

__device__ inline f32x4 vzero4() { f32x4 z; z[0]=0.f; z[1]=0.f; z[2]=0.f; z[3]=0.f; return z; }

__device__ inline float4 ld_half4(const __half* p) {
  float2 a = __half22float2(*(const __half2*)p);
  float2 b = __half22float2(*(const __half2*)(p + 2));
  return make_float4(a.x, a.y, b.x, b.y);
}

__device__ inline void st_half4(__half* p, float4 v) {
  *(__half2*)p       = __floats2half2_rn(v.x, v.y);
  *(__half2*)(p + 2) = __floats2half2_rn(v.z, v.w);
}

// async global->LDS 16B per lane: lds dest = (wave-uniform base) + lane*16B
__device__ __forceinline__ void gll16(const void* g, void* lds) {
  __builtin_amdgcn_global_load_lds(
      (__attribute__((address_space(1))) void*)g,
      (__attribute__((address_space(3))) void*)lds,
      16, 0, 0);
}

// ---------------- utility ----------------
__global__ void k_zero(float* __restrict__ s) { s[blockIdx.x*256 + threadIdx.x] = 0.f; }

__global__ void k_sentinel(float* __restrict__ out, int n, float val) {
  for (int i = blockIdx.x*blockDim.x + threadIdx.x; i < n; i += gridDim.x*blockDim.x)
    out[i] = val;
}

// src[l][co][ci][kk] (co=128,ci=12,kk=9) -> dst[(kk*12+ci)*128+co]  (conv1 f32 path)
__global__ void k_wprep(const float* __restrict__ src, float* __restrict__ dst, int L, int Cin) {
  int total = L * 128 * Cin * 9;
  for (int idx = blockIdx.x*blockDim.x + threadIdx.x; idx < total; idx += gridDim.x*blockDim.x) {
    int kk = idx % 9; int t2 = idx / 9;
    int ci = t2 % Cin; t2 /= Cin;
    int co = t2 % 128; int l  = t2 / 128;
    dst[((size_t)(l*9 + kk)*Cin + ci)*128 + co] = src[idx];
  }
}

// src[l][co][ci][kk] (128x128x9) -> dst f16 [(l*128+co)*1152 + kk*128 + ci]
__global__ void k_wprep16(const float* __restrict__ src, __half* __restrict__ dst, int L) {
  int total = L * 128 * 128 * 9;
  for (int idx = blockIdx.x*blockDim.x + threadIdx.x; idx < total; idx += gridDim.x*blockDim.x) {
    int kk = idx % 9; int t2 = idx / 9;
    int ci = t2 % 128; t2 /= 128;
    int co = t2 % 128; int l  = t2 / 128;
    dst[((size_t)(l*128 + co))*1152 + kk*128 + ci] = __float2half(src[idx]);
  }
}

// W f32 [K][N] -> WT f16 [N][K]
__global__ void k_wt16(const float* __restrict__ W, __half* __restrict__ WT, int K, int N) {
  int total = K * N;
  for (int idx = blockIdx.x*blockDim.x + threadIdx.x; idx < total; idx += gridDim.x*blockDim.x) {
    int k = idx / N, n = idx % N;
    WT[(size_t)n*K + k] = __float2half(W[idx]);
  }
}

// One layer's qkv/proj/fc1/fc2 f32 -> transposed f16 into wTt.
// q columns (n<512) of Wq and qkv bias are pre-scaled by hd^-0.5 = 0.125.
__global__ void k_wt16x4(const float* __restrict__ Wq, const float* __restrict__ Wp,
                         const float* __restrict__ W1, const float* __restrict__ W2,
                         const float* __restrict__ bq,
                         __half* __restrict__ wTt, float* __restrict__ biasbuf) {
  int gid0 = blockIdx.x*blockDim.x + threadIdx.x;
  if (gid0 < 1536) biasbuf[gid0] = bq[gid0] * (gid0 < 512 ? 0.125f : 1.f);
  const int TOT = 786432 + 3*262144;
  for (int idx = gid0; idx < TOT; idx += gridDim.x*blockDim.x) {
    if (idx < 786432) {
      int k = idx / 1536, n = idx % 1536;
      float v = Wq[idx] * (n < 512 ? 0.125f : 1.f);
      wTt[T_QKV + (size_t)n*512 + k] = __float2half(v);
    } else {
      int r0 = idx - 786432;
      int s = r0 / 262144, r = r0 % 262144;
      int k = r / 512, n = r % 512;
      const float* W = (s == 0) ? Wp : (s == 1) ? W1 : W2;
      wTt[T_PRJ + s*262144 + (size_t)n*512 + k] = __float2half(W[r]);
    }
  }
}

// ---------------- encode + conv1 (one-hot lookup), output f16 act ----------------
__global__ __launch_bounds__(256) void k_conv1(const int* __restrict__ xin,
    const float* __restrict__ wT1, const float* __restrict__ b1,
    __half* __restrict__ out) {
  __shared__ int s_w[64], s_b[64];
  int b = blockIdx.x, t = threadIdx.x;
  if (t < 64) { s_w[t] = xin[b*128 + t]; s_b[t] = xin[b*128 + 64 + t]; }
  __syncthreads();
  int p = t >> 2, i = t & 3;
  int y = p >> 3, x = p & 7;
  float acc[32];
  #pragma unroll
  for (int j = 0; j < 32; ++j) acc[j] = b1[i*32 + j];
  #pragma unroll
  for (int kk = 0; kk < 9; ++kk) {
    int ny = y + kk/3 - 1, nx = x + kk%3 - 1;
    if (ny < 0 || ny > 7 || nx < 0 || nx > 7) continue;
    int np = ny*8 + nx;
    int wp = s_w[np], bp = s_b[np];
    if (wp >= 1 && wp <= 6) {
      const float* w = &wT1[(size_t)(kk*12 + (wp-1))*128 + i*32];
      #pragma unroll
      for (int j = 0; j < 32; ++j) acc[j] += w[j];
    }
    if (bp >= 1 && bp <= 6) {
      const float* w = &wT1[(size_t)(kk*12 + 6 + (bp-1))*128 + i*32];
      #pragma unroll
      for (int j = 0; j < 32; ++j) acc[j] += w[j];
    }
  }
  __half* o = &out[((size_t)b*64 + p)*128 + i*32];
  #pragma unroll
  for (int j = 0; j < 16; ++j)
    *(__half2*)&o[j*2] = __floats2half2_rn(acc[j*2], acc[j*2+1]);
}

// ---------------- MFMA residual 3x3 conv + fused BN stats ----------------
#define IMG_W 136

__global__ __launch_bounds__(256) void k_conv_mfma(const __half* __restrict__ in,
    const __half* __restrict__ wT /* [128][1152] f16 */, const float* __restrict__ bias,
    const float* __restrict__ stats_in, const float* __restrict__ g,
    const float* __restrict__ bb, int use_bn, __half* __restrict__ out,
    float* __restrict__ stats_out) {
  __shared__ __align__(16) _Float16 s_img[2*65*IMG_W];  // 35,360 B (row 64 = zeros)
  __shared__ __align__(16) _Float16 s_B[2][4096];       // 2 x [128][32] linear, 16 KB
  __shared__ float s_sum[128], s_sq[128];               // 1 KB
  __shared__ float s_bnp[256];                          // 1 KB
  int b2 = blockIdx.x, t = threadIdx.x;
  int w = t >> 6, lane = t & 63;

  auto issueB = [&](int win, int buf) {
    #pragma unroll
    for (int i = 0; i < 2; ++i) {
      int rbase = (w*2 + i)*16;
      const __half* g2 = &wT[(size_t)(rbase + (lane>>2))*1152 + win*32 + (lane&3)*8];
      gll16(g2, &s_B[buf][rbase*32]);
    }
  };
  issueB(0, 0);

  if (use_bn && t < 128) {
    const float invN = 1.f / (float)NPOSR;
    float m = stats_in[t] * invN;
    float vv = stats_in[128+t] * invN - m*m;
    float sc = g[t] * rsqrtf(vv + 1e-5f);
    s_bnp[t] = sc;
    s_bnp[128+t] = bb[t] - m*sc;
  }
  __syncthreads();

  for (int idx4 = t; idx4 < 4096; idx4 += 256) {
    int img = idx4 >> 11, rr = (idx4 >> 5) & 63, c4 = (idx4 & 31) * 4;
    const __half* src = &in[((size_t)(b2*2 + img)*64 + rr)*128 + c4];
    float4 vv4 = ld_half4(src);
    float v0 = vv4.x, v1 = vv4.y, v2 = vv4.z, v3 = vv4.w;
    if (use_bn) {
      v0 = s_bnp[c4+0]*v0 + s_bnp[128+c4+0];
      v1 = s_bnp[c4+1]*v1 + s_bnp[128+c4+1];
      v2 = s_bnp[c4+2]*v2 + s_bnp[128+c4+2];
      v3 = s_bnp[c4+3]*v3 + s_bnp[128+c4+3];
    }
    f16x4 h;
    h[0] = (_Float16)fmaxf(v0, 0.f); h[1] = (_Float16)fmaxf(v1, 0.f);
    h[2] = (_Float16)fmaxf(v2, 0.f); h[3] = (_Float16)fmaxf(v3, 0.f);
    *(f16x4*)&s_img[(img*65 + rr)*IMG_W + c4] = h;
  }
  {
    int img = t >> 7, c = t & 127;
    s_img[(img*65 + 64)*IMG_W + c] = (_Float16)0.f;
    if (t < 128) { s_sum[t] = 0.f; s_sq[t] = 0.f; }
  }
  int wm = (w >> 1)*64, wn = (w & 1)*64;
  int fr = lane & 15, fq = lane >> 4;
  int imgo[4], yy[4], xx_[4];
  #pragma unroll
  for (int mt = 0; mt < 4; ++mt) {
    int r = wm + mt*16 + fr;
    imgo[mt] = r >> 6; int p = r & 63; yy[mt] = p >> 3; xx_[mt] = p & 7;
  }
  f32x4 acc[4][4];
  #pragma unroll
  for (int mt = 0; mt < 4; ++mt)
    #pragma unroll
    for (int nt = 0; nt < 4; ++nt) acc[mt][nt] = vzero4();
  __syncthreads();   // image + weight window 0 ready

  #pragma unroll
  for (int kk = 0; kk < 9; ++kk) {
    int dy = kk/3 - 1, dx = kk%3 - 1;
    const _Float16* abase[4];
    #pragma unroll
    for (int mt = 0; mt < 4; ++mt) {
      int ny = yy[mt] + dy, nx = xx_[mt] + dx;
      int row = ((unsigned)ny < 8u && (unsigned)nx < 8u) ? (ny*8 + nx) : 64;
      abase[mt] = &s_img[(imgo[mt]*65 + row)*IMG_W];
    }
    #pragma unroll
    for (int q = 0; q < 4; ++q) {
      int win = kk*4 + q;
      int buf = win & 1;
      if (win + 1 < 36) issueB(win + 1, buf ^ 1);
      f16x8 af[4], bf[4];
      #pragma unroll
      for (int mt = 0; mt < 4; ++mt) af[mt] = *(const f16x8*)&abase[mt][q*32 + fq*8];
      #pragma unroll
      for (int nt = 0; nt < 4; ++nt) bf[nt] = *(const f16x8*)&s_B[buf][(wn + nt*16 + fr)*32 + fq*8];
      #pragma unroll
      for (int mt = 0; mt < 4; ++mt)
        #pragma unroll
        for (int nt = 0; nt < 4; ++nt)
          acc[mt][nt] = __builtin_amdgcn_mfma_f32_16x16x32_f16(af[mt], bf[nt], acc[mt][nt], 0, 0, 0);
      __syncthreads();
    }
  }
  #pragma unroll
  for (int nt = 0; nt < 4; ++nt) {
    int col = wn + nt*16 + fr;
    float bv = bias[col];
    float s = 0.f, q = 0.f;
    #pragma unroll
    for (int mt = 0; mt < 4; ++mt) {
      int rbase = wm + mt*16 + fq*4;
      #pragma unroll
      for (int j = 0; j < 4; ++j) {
        int r = rbase + j;
        int img = r >> 6, p = r & 63;
        float v = acc[mt][nt][j] + bv;
        s += v; q += v*v;
        out[((size_t)(b2*2 + img)*64 + p)*128 + col] = __float2half(v);
      }
    }
    s += __shfl_xor(s, 16); s += __shfl_xor(s, 32);
    q += __shfl_xor(q, 16); q += __shfl_xor(q, 32);
    if (fq == 0) { atomicAdd(&s_sum[col], s); atomicAdd(&s_sq[col], q); }
  }
  __syncthreads();
  if (t < 128) {
    atomicAdd(&stats_out[t], s_sum[t]);
    atomicAdd(&stats_out[128 + t], s_sq[t]);
  }
}

// ---------------- t = window_partition(act + bn2(z1h)) + pos, in-place per image (f16) ----------------
__global__ __launch_bounds__(256) void k_make_t(__half* __restrict__ act,
    const __half* __restrict__ z1h, const float* __restrict__ stats_in,
    const float* __restrict__ g, const float* __restrict__ bb,
    const float* __restrict__ pos) {
  __shared__ float s_t[8192];
  __shared__ float s_bnp[256];
  int b = blockIdx.x, t = threadIdx.x;
  if (t < 128) {
    const float invN = 1.f / (float)NPOSR;
    float m = stats_in[t] * invN;
    float vv = stats_in[128+t] * invN - m*m;
    float sc = g[t] * rsqrtf(vv + 1e-5f);
    s_bnp[t] = sc;
    s_bnp[128+t] = bb[t] - m*sc;
  }
  __syncthreads();
  for (int idx4 = t; idx4 < 2048; idx4 += 256) {
    int n = idx4 >> 7, d4 = idx4 & 127;
    int d = d4*4, c = d & 127, q = d >> 7;
    int y = ((n>>2)<<1) + (q>>1), xx = ((n&3)<<1) + (q&1);
    size_t sp = ((size_t)b*64 + y*8 + xx)*128 + c;
    float4 a  = ld_half4(&act[sp]);
    float4 z  = ld_half4(&z1h[sp]);
    float4 sc = *(const float4*)&s_bnp[c];
    float4 sh = *(const float4*)&s_bnp[128+c];
    float4 pe = *(const float4*)&pos[n*512 + d];
    float4 o;
    o.x = a.x + sc.x*z.x + sh.x + pe.x;
    o.y = a.y + sc.y*z.y + sh.y + pe.y;
    o.z = a.z + sc.z*z.z + sh.z + pe.z;
    o.w = a.w + sc.w*z.w + sh.w + pe.w;
    *(float4*)&s_t[n*512 + d] = o;
  }
  __syncthreads();
  for (int idx8 = t; idx8 < 1024; idx8 += 256) {
    float4 v0 = *(float4*)&s_t[idx8*8];
    float4 v1 = *(float4*)&s_t[idx8*8 + 4];
    __half* o = &act[(size_t)b*8192 + idx8*8];
    st_half4(o, v0);
    st_half4(o + 4, v1);
  }
}

// ---------------- windowed attention from qkvbuf (1 image per block) ----------------
#define QS 1544   // padded row stride (halfs), 16B-aligned rows

__global__ __launch_bounds__(256) void k_attn16(const __half* __restrict__ qkvbuf,
    __half* __restrict__ attnout) {
  __shared__ __align__(16) _Float16 s_qkv[16][QS];   // 49,408 B
  __shared__ float S[8][16][17];                     //  8,704 B
  int img = blockIdx.x, t = threadIdx.x;
  const __half* src = qkvbuf + (size_t)img*16*1536;
  #pragma unroll
  for (int i = 0; i < 12; ++i) {
    int lin = t + i*256;
    int row = lin / 192, c8 = lin % 192;
    *(f16x8*)&s_qkv[row][c8*8] = *(const f16x8*)&src[(size_t)row*1536 + c8*8];
  }
  __syncthreads();
  {
    int h = t >> 5, qi = (t >> 1) & 15, ko = (t & 1) * 8;
    int rot = t & 31;
    float acc[8];
    #pragma unroll
    for (int k = 0; k < 8; ++k) acc[k] = 0.f;
    const __half2* qr = (const __half2*)&s_qkv[qi][h*64];
    for (int i2 = 0; i2 < 32; ++i2) {
      int d2 = (i2 + rot) & 31;
      float2 q2 = __half22float2(qr[d2]);
      #pragma unroll
      for (int k = 0; k < 8; ++k) {
        float2 k2 = __half22float2(*(const __half2*)&s_qkv[ko + k][512 + h*64 + d2*2]);
        acc[k] += q2.x*k2.x + q2.y*k2.y;
      }
    }
    #pragma unroll
    for (int k = 0; k < 8; ++k) S[h][qi][ko + k] = acc[k];
  }
  __syncthreads();
  if (t < 128) {
    int h = t >> 4, qi = t & 15;
    float* Sr = S[h][qi];
    float mx = -1e30f;
    #pragma unroll
    for (int ki = 0; ki < 16; ++ki) mx = fmaxf(mx, Sr[ki]);
    float sm = 0.f; float e[16];
    #pragma unroll
    for (int ki = 0; ki < 16; ++ki) { e[ki] = expf(Sr[ki] - mx); sm += e[ki]; }
    float inv = 1.f / sm;
    #pragma unroll
    for (int ki = 0; ki < 16; ++ki) Sr[ki] = e[ki]*inv;
  }
  __syncthreads();
  {
    int qi = t >> 4, rem = t & 15;
    int h = rem >> 1, dhb = (rem & 1) * 32;
    int rot = (t >> 2) & 15;
    float P[16];
    #pragma unroll
    for (int k = 0; k < 16; ++k) P[k] = S[h][qi][(k + rot) & 15];
    __half* orow = attnout + ((size_t)img*16 + qi)*512 + h*64 + dhb;
    #pragma unroll
    for (int j = 0; j < 16; ++j) {
      int dh = dhb + 2*j;
      float a0 = 0.f, a1 = 0.f;
      #pragma unroll
      for (int kk2 = 0; kk2 < 16; ++kk2) {
        int ki = (kk2 + rot) & 15;
        float2 v2 = __half22float2(*(const __half2*)&s_qkv[ki][1024 + h*64 + dh]);
        a0 += P[kk2]*v2.x; a1 += P[kk2]*v2.y;
      }
      *(__half2*)&orow[2*j] = __floats2half2_rn(a0, a1);
    }
  }
}

// ---------------- generic MFMA GEMM: C = act(A@B + bias) ----------------
// SWAP=1: bm <- blockIdx.y, bn <- blockIdx.x (consecutive blocks share the A tile).
template<int MTI, int NTI, int A16, int B16, int RELU, int OUT16, int SWAP>
__global__ __launch_bounds__(256) void k_mgemm(const void* __restrict__ Ap,
    const void* __restrict__ Bp, const float* __restrict__ bias,
    void* __restrict__ Cp, int M, int N, int K) {
  constexpr int BM = MTI*32;
  constexpr int BN = NTI*32;
  __shared__ __align__(16) _Float16 sA[2][BM*32];
  __shared__ __align__(16) _Float16 sB[2][BN*32];
  int t = threadIdx.x;
  int bm = (SWAP ? blockIdx.y : blockIdx.x) * BM;
  int bn = (SWAP ? blockIdx.x : blockIdx.y) * BN;
  int w = t >> 6, lane = t & 63;
  int wm = (w >> 1) * (MTI*16), wn = (w & 1) * (NTI*16);
  int fr = lane & 15, fq = lane >> 4;

  auto stageA = [&](int k0, int buf) {
    if (A16) {
      const __half* A = (const __half*)Ap;
      constexpr int NI = MTI/2;
      #pragma unroll
      for (int i = 0; i < NI; ++i) {
        int rbase = (w*NI + i)*16;
        gll16(&A[(size_t)(bm + rbase + (lane>>2))*K + k0 + (lane&3)*8],
              &sA[buf][rbase*32]);
      }
    } else {
      const float* A = (const float*)Ap;
      if (MTI == 4) {
        int srow = t >> 1, skh = (t & 1) * 16;
        const float4* src = (const float4*)&A[(size_t)(bm + srow)*K + k0 + skh];
        float4 v0 = src[0], v1 = src[1], v2 = src[2], v3 = src[3];
        f16x8 h0, h1;
        h0[0]=(_Float16)v0.x; h0[1]=(_Float16)v0.y; h0[2]=(_Float16)v0.z; h0[3]=(_Float16)v0.w;
        h0[4]=(_Float16)v1.x; h0[5]=(_Float16)v1.y; h0[6]=(_Float16)v1.z; h0[7]=(_Float16)v1.w;
        h1[0]=(_Float16)v2.x; h1[1]=(_Float16)v2.y; h1[2]=(_Float16)v2.z; h1[3]=(_Float16)v2.w;
        h1[4]=(_Float16)v3.x; h1[5]=(_Float16)v3.y; h1[6]=(_Float16)v3.z; h1[7]=(_Float16)v3.w;
        *(f16x8*)&sA[buf][srow*32 + skh]     = h0;
        *(f16x8*)&sA[buf][srow*32 + skh + 8] = h1;
      } else {
        int srow = t >> 2, g8 = (t & 3) * 8;
        const float4* src = (const float4*)&A[(size_t)(bm + srow)*K + k0 + g8];
        float4 v0 = src[0], v1 = src[1];
        f16x8 h0;
        h0[0]=(_Float16)v0.x; h0[1]=(_Float16)v0.y; h0[2]=(_Float16)v0.z; h0[3]=(_Float16)v0.w;
        h0[4]=(_Float16)v1.x; h0[5]=(_Float16)v1.y; h0[6]=(_Float16)v1.z; h0[7]=(_Float16)v1.w;
        *(f16x8*)&sA[buf][srow*32 + g8] = h0;
      }
    }
  };
  auto stageB = [&](int k0, int buf) {
    if (B16) {
      const __half* BT = (const __half*)Bp;
      constexpr int NBI = NTI/2;
      #pragma unroll
      for (int i = 0; i < NBI; ++i) {
        int rbase = (w*NBI + i)*16;
        gll16(&BT[(size_t)(bn + rbase + (lane>>2))*K + k0 + (lane&3)*8],
              &sB[buf][rbase*32]);
      }
    } else {
      const float* B = (const float*)Bp;
      int kr = t >> 3, n0 = (t & 7) * 16;
      #pragma unroll
      for (int g = 0; g < 4; ++g) {
        float4 v = *(const float4*)&B[(size_t)(k0 + kr)*N + bn + n0 + g*4];
        sB[buf][(n0+g*4+0)*32 + kr] = (_Float16)v.x;
        sB[buf][(n0+g*4+1)*32 + kr] = (_Float16)v.y;
        sB[buf][(n0+g*4+2)*32 + kr] = (_Float16)v.z;
        sB[buf][(n0+g*4+3)*32 + kr] = (_Float16)v.w;
      }
    }
  };

  f32x4 acc[MTI][NTI];
  #pragma unroll
  for (int mt = 0; mt < MTI; ++mt)
    #pragma unroll
    for (int nt = 0; nt < NTI; ++nt) acc[mt][nt] = vzero4();

  stageA(0, 0); stageB(0, 0);
  __syncthreads();
  int KW = K >> 5;
  for (int kw = 0; kw < KW; ++kw) {
    int buf = kw & 1;
    if (kw + 1 < KW) { stageA((kw+1)*32, buf ^ 1); stageB((kw+1)*32, buf ^ 1); }
    f16x8 af[MTI], bf[NTI];
    #pragma unroll
    for (int mt = 0; mt < MTI; ++mt) af[mt] = *(const f16x8*)&sA[buf][(wm + mt*16 + fr)*32 + fq*8];
    #pragma unroll
    for (int nt = 0; nt < NTI; ++nt) bf[nt] = *(const f16x8*)&sB[buf][(wn + nt*16 + fr)*32 + fq*8];
    #pragma unroll
    for (int mt = 0; mt < MTI; ++mt)
      #pragma unroll
      for (int nt = 0; nt < NTI; ++nt)
        acc[mt][nt] = __builtin_amdgcn_mfma_f32_16x16x32_f16(af[mt], bf[nt], acc[mt][nt], 0, 0, 0);
    __syncthreads();
  }
  #pragma unroll
  for (int mt = 0; mt < MTI; ++mt)
    #pragma unroll
    for (int nt = 0; nt < NTI; ++nt) {
      int col = bn + wn + nt*16 + fr;
      float bv = bias[col];
      #pragma unroll
      for (int j = 0; j < 4; ++j) {
        int row = bm + wm + mt*16 + fq*4 + j;
        float v = acc[mt][nt][j] + bv;
        if (RELU) v = fmaxf(v, 0.f);
        if (OUT16) ((__half*)Cp)[(size_t)row*N + col] = __float2half(v);
        else       ((float*)Cp)[(size_t)row*N + col] = v;
      }
    }
}

// ---------------- t2 = t(f16) + LN(gemm_out): writes f16 t2 ----------------
__global__ __launch_bounds__(256) void k_lnres(const __half* __restrict__ pout,
    const __half* __restrict__ tact, __half* __restrict__ t2h) {
  int t = threadIdx.x;
  int tok = blockIdx.x*4 + (t >> 6);
  int lane = t & 63;
  f16x8 hv = *(const f16x8*)&pout[(size_t)tok*512 + lane*8];
  float v[8]; float s1 = 0.f, s2 = 0.f;
  #pragma unroll
  for (int j = 0; j < 8; ++j) { v[j] = (float)hv[j]; s1 += v[j]; s2 += v[j]*v[j]; }
  #pragma unroll
  for (int m = 32; m >= 1; m >>= 1) { s1 += __shfl_xor(s1, m); s2 += __shfl_xor(s2, m); }
  float mean = s1 * (1.f/512.f);
  float var  = s2 * (1.f/512.f) - mean*mean;
  float rs = rsqrtf(var + 1e-6f);
  f16x8 av = *(const f16x8*)&tact[(size_t)tok*512 + lane*8];
  f16x8 o16;
  #pragma unroll
  for (int j = 0; j < 8; ++j) {
    float t2 = (float)av[j] + (v[j] - mean)*rs;
    o16[j] = (_Float16)t2;
  }
  *(f16x8*)&t2h[(size_t)tok*512 + lane*8] = o16;
}

// ---------------- t2(f16) + LN(fc2out), window_reverse to spatial (f16), per image ----------------
__global__ __launch_bounds__(256) void k_lnres2(const __half* __restrict__ fout,
    const __half* __restrict__ t2h, __half* __restrict__ actimg) {
  __shared__ float s_t2[8192];
  int bimg = blockIdx.x, t = threadIdx.x;
  int lane = t & 63;
  for (int tg = 0; tg < 4; ++tg) {
    int n = tg*4 + (t >> 6);
    size_t row = (size_t)bimg*16 + n;
    f16x8 hv = *(const f16x8*)&fout[row*512 + lane*8];
    float v[8]; float s1 = 0.f, s2 = 0.f;
    #pragma unroll
    for (int j = 0; j < 8; ++j) { v[j] = (float)hv[j]; s1 += v[j]; s2 += v[j]*v[j]; }
    #pragma unroll
    for (int m = 32; m >= 1; m >>= 1) { s1 += __shfl_xor(s1, m); s2 += __shfl_xor(s2, m); }
    float mean = s1 * (1.f/512.f);
    float var  = s2 * (1.f/512.f) - mean*mean;
    float rs = rsqrtf(var + 1e-6f);
    f16x8 tv = *(const f16x8*)&t2h[row*512 + lane*8];
    #pragma unroll
    for (int j = 0; j < 8; ++j)
      s_t2[n*512 + lane*8 + j] = (float)tv[j] + (v[j] - mean)*rs;
  }
  __syncthreads();
  for (int idx = t; idx < 1024; idx += 256) {
    int p = idx >> 4, c = (idx & 15)*8;
    int y = p >> 3, x = p & 7;
    int n = (y >> 1)*4 + (x >> 1);
    int d = ((y & 1)*2 + (x & 1))*128 + c;
    float4 v0 = *(float4*)&s_t2[n*512 + d];
    float4 v1 = *(float4*)&s_t2[n*512 + d + 4];
    __half* o = &actimg[(size_t)bimg*8192 + p*128 + c];
    st_half4(o, v0);
    st_half4(o + 4, v1);
  }
}

// ---------------- row softmax (640) ----------------
__global__ __launch_bounds__(256) void k_softmax(const float* __restrict__ logits, float* __restrict__ out) {
  int b = blockIdx.x, t = threadIdx.x;
  __shared__ float red[256];
  float m = -1e30f;
  for (int j = t; j < 640; j += 256) m = fmaxf(m, logits[(size_t)b*640 + j]);
  red[t] = m; __syncthreads();
  for (int s = 128; s > 0; s >>= 1) { if (t < s) red[t] = fmaxf(red[t], red[t+s]); __syncthreads(); }
  m = red[0]; __syncthreads();
  float sum = 0.f;
  for (int j = t; j < 640; j += 256) sum += expf(logits[(size_t)b*640 + j] - m);
  red[t] = sum; __syncthreads();
  for (int s = 128; s > 0; s >>= 1) { if (t < s) red[t] += red[t+s]; __syncthreads(); }
  float inv = 1.f / red[0];
  for (int j = t; j < 640; j += 256) out[(size_t)b*640 + j] = expf(logits[(size_t)b*640 + j] - m) * inv;
}

// ---------------- host ----------------
extern "C" void kernel_launch(void* const* d_in, const int* in_sizes, int n_in,
                              void* d_out, int out_size, void* d_ws, size_t ws_size,
                              hipStream_t stream) {
  (void)in_sizes; (void)n_in;
  float* out = (float*)d_out;
  if (ws_size < (size_t)WS_NEED_FLOATS * 4) {
    k_sentinel<<<2048, 256, 0, stream>>>(out, out_size, (float)(ws_size >> 20));
    return;
  }

  const int*   x       = (const int*)d_in[0];
  const float* pos     = (const float*)d_in[1];
  const float* conv1_w = (const float*)d_in[2];
  const float* conv1_b = (const float*)d_in[3];
  const float* rb1_w   = (const float*)d_in[4];
  const float* rb1_b   = (const float*)d_in[5];
  const float* bn1_g   = (const float*)d_in[6];
  const float* bn1_b   = (const float*)d_in[7];
  const float* rb2_w   = (const float*)d_in[8];
  const float* rb2_b   = (const float*)d_in[9];
  const float* bn2_g   = (const float*)d_in[10];
  const float* bn2_b   = (const float*)d_in[11];
  const float* qkv_w   = (const float*)d_in[12];
  const float* qkv_b   = (const float*)d_in[13];
  const float* proj_w  = (const float*)d_in[14];
  const float* proj_b  = (const float*)d_in[15];
  const float* fc1_w   = (const float*)d_in[16];
  const float* fc1_b   = (const float*)d_in[17];
  const float* fc2_w   = (const float*)d_in[18];
  const float* fc2_b   = (const float*)d_in[19];
  const float* lin1_w  = (const float*)d_in[20];
  const float* lin1_b  = (const float*)d_in[21];
  const float* lin2_w  = (const float*)d_in[22];
  const float* lin2_b  = (const float*)d_in[23];

  float*  ws    = (float*)d_ws;
  __half* act16 = (__half*)(ws + OFF_ACT);
  __half* big2h = (__half*)(ws + OFF_BIG2);
  float*  wT1   = ws + OFF_WT1;
  __half* wTa16 = (__half*)(ws + OFF_WTA);
  __half* wTb16 = (__half*)(ws + OFF_WTB);
  __half* wTt   = (__half*)(ws + OFF_WTT);
  float*  stats20 = ws + OFF_STATS;     // 20 x 256
  float*  biasbuf = ws + OFF_BIAS;

  __half* z1h     = big2h;
  __half* qkvbuf  = big2h + H_QKVB;
  __half* attnout = big2h + H_ATT;
  __half* projout = big2h + H_QKVB;     // overlays qkvbuf (dead after attn)
  __half* t2h     = big2h + H_T2H;      // overlays qkvbuf tail (dead after attn)
  __half* h1      = attnout;            // attnout dead after proj gemm
  __half* fc2out  = projout;            // projout dead after lnres
  __half* qkvT    = wTt + T_QKV;
  __half* projT   = wTt + T_PRJ;
  __half* fc1T    = wTt + T_F1;
  __half* fc2T    = wTt + T_F2;
  __half* L1h     = big2h;
  float*  logits  = (float*)(big2h + H_LOG);
  __half* lin2T   = wTt;

  k_zero<<<20, 256, 0, stream>>>(stats20);
  k_wprep<<<64, 256, 0, stream>>>(conv1_w, wT1, 1, 12);
  k_wprep16<<<2048, 256, 0, stream>>>(rb1_w, wTa16, 10);
  k_wprep16<<<2048, 256, 0, stream>>>(rb2_w, wTb16, 10);
  k_conv1<<<NBATCH, 256, 0, stream>>>(x, wT1, conv1_b, act16);

  for (int l = 0; l < 10; ++l) {
    float* statsA = stats20 + (size_t)(2*l)*256;
    float* statsB = stats20 + (size_t)(2*l + 1)*256;
    k_conv_mfma<<<NBATCH/2, 256, 0, stream>>>(act16, wTa16 + (size_t)l*147456,
        rb1_b + l*128, (const float*)nullptr, (const float*)nullptr,
        (const float*)nullptr, 0, z1h, statsA);
    k_conv_mfma<<<NBATCH/2, 256, 0, stream>>>(z1h, wTb16 + (size_t)l*147456,
        rb2_b + l*128, statsA, bn1_g + l*128, bn1_b + l*128, 1, z1h, statsB);
    k_make_t<<<NBATCH, 256, 0, stream>>>(act16, z1h, statsB, bn2_g + l*128,
        bn2_b + l*128, pos);   // z1h dead after this

    k_wt16x4<<<2048, 256, 0, stream>>>(qkv_w + (size_t)l*786432,
        proj_w + (size_t)l*262144, fc1_w + (size_t)l*262144, fc2_w + (size_t)l*262144,
        qkv_b + l*1536, wTt, biasbuf);

    for (int ch = 0; ch < NBATCH/CH; ++ch) {
      __half* tchunk = act16 + (size_t)ch*CH*8192;
      // qkv = t @ Wqkv + b (q pre-scaled); SWAP grid: A tile L2-hot, weights sweep
      k_mgemm<4,4,1,1,0,1,1><<<dim3(12, CHT/128), 256, 0, stream>>>(tchunk, qkvT,
          biasbuf, qkvbuf, CHT, 1536, 512);
      k_attn16<<<CH, 256, 0, stream>>>(qkvbuf, attnout);
      k_mgemm<4,4,1,1,0,1,1><<<dim3(4, CHT/128), 256, 0, stream>>>(attnout, projT,
          proj_b + l*512, projout, CHT, 512, 512);
      k_lnres<<<CHT/4, 256, 0, stream>>>(projout, tchunk, t2h);
      k_mgemm<4,4,1,1,1,1,1><<<dim3(4, CHT/128), 256, 0, stream>>>(t2h, fc1T,
          fc1_b + l*512, h1, CHT, 512, 512);
      k_mgemm<4,4,1,1,0,1,1><<<dim3(4, CHT/128), 256, 0, stream>>>(h1, fc2T,
          fc2_b + l*512, fc2out, CHT, 512, 512);
      k_lnres2<<<CH, 256, 0, stream>>>(fc2out, t2h, tchunk);
    }
  }
  k_mgemm<2,4,1,0,1,1,0><<<dim3(4096/64, 8), 256, 0, stream>>>(act16, lin1_w, lin1_b, L1h,
      4096, 1024, 8192);
  k_wt16<<<512, 256, 0, stream>>>(lin2_w, lin2T, 1024, 640);
  k_mgemm<2,4,1,1,0,0,0><<<dim3(4096/64, 5), 256, 0, stream>>>(L1h, lin2T, lin2_b, logits,
      4096, 640, 1024);
  k_softmax<<<NBATCH, 256, 0, stream>>>(logits, out);
}

// Round 18
// 8428.197 us; speedup vs baseline: 1.0507x; 1.0507x over previous
//
#include <hip/hip_runtime.h>
#include <hip/hip_fp16.h>
#include <math.h>

// betaChessAI forward: 10 blocks of {conv-bn-conv-bn residual, windowed attention, MLP}
// R18 = exact revert to R16 (8.47ms best-known). R17's SWAP grid axis regressed
// (A re-reads were L3-absorbed; swapping broke write locality) — falsified and removed.
// Layouts:
//   spatial activations: act16[(b*64 + p)*128 + c], p = y*8+x   (== feat layout for head)
//   token activations:   t[(b*16 + n)*512 + d],  d = (p1*2+p2)*128 + c, n = hy*4+wx
// Workspace (float slots), ~147 MB.

#define NBATCH 4096
#define NPOSR  (NBATCH*64)
#define CH     1024                    // images per attention chunk
#define CHT    (CH*16)                 // tokens per chunk = 16384

#define OFF_ACT   0                    // act16: 33,554,432 halfs = 16,777,216 f32 slots
#define OFF_BIG2  16777216
#define OFF_WT1   (OFF_BIG2 + 16777216)
#define OFF_WTA   (OFF_WT1 + 13824)    // f16 [10][128][1152] in 737,280 f32 slots
#define OFF_WTB   (OFF_WTA + 737280)
#define OFF_WTT   (OFF_WTB + 737280)   // f16 transformer weights, 1,572,864 halfs
#define OFF_STATS (OFF_WTT + 786432)   // 20 slots x 256 floats
#define OFF_BIAS  (OFF_STATS + 5120)   // scaled qkv bias, 1536 f32
#define WS_NEED_FLOATS (OFF_BIAS + 1536)

// big2 half-offsets (transformer phase, CH=1024):
//   conv phase: z1h = full big2 [0, 33.55M)
//   chunk loop: qkvbuf [0, 25.17M) ; attnout [25.17M, 33.55M) ; t2h [8.39M, 16.78M)
#define H_QKVB 0
#define H_ATT  25165824
#define H_T2H  8388608
#define H_LOG  8388608                 // head phase: logits f32 at halfs [8.39M, 13.63M)

// wTt half-offsets
#define T_QKV  0
#define T_PRJ  786432
#define T_F1   1048576
#define T_F2   1310720

typedef _Float16 f16x8 __attribute__((ext_vector_type(8)));
typedef _Float16 f16x4 __attribute__((ext_vector_type(4)));
typedef float f32x4 __attribute__((ext_vector_type(4)));

__device__ inline f32x4 vzero4() { f32x4 z; z[0]=0.f; z[1]=0.f; z[2]=0.f; z[3]=0.f; return z; }

__device__ inline float4 ld_half4(const __half* p) {
  float2 a = __half22float2(*(const __half2*)p);
  float2 b = __half22float2(*(const __half2*)(p + 2));
  return make_float4(a.x, a.y, b.x, b.y);
}

__device__ inline void st_half4(__half* p, float4 v) {
  *(__half2*)p       = __floats2half2_rn(v.x, v.y);
  *(__half2*)(p + 2) = __floats2half2_rn(v.z, v.w);
}

// async global->LDS 16B per lane: lds dest = (wave-uniform base) + lane*16B
__device__ __forceinline__ void gll16(const void* g, void* lds) {
  __builtin_amdgcn_global_load_lds(
      (__attribute__((address_space(1))) void*)g,
      (__attribute__((address_space(3))) void*)lds,
      16, 0, 0);
}

// ---------------- utility ----------------
__global__ void k_zero(float* __restrict__ s) { s[blockIdx.x*256 + threadIdx.x] = 0.f; }

__global__ void k_sentinel(float* __restrict__ out, int n, float val) {
  for (int i = blockIdx.x*blockDim.x + threadIdx.x; i < n; i += gridDim.x*blockDim.x)
    out[i] = val;
}

// src[l][co][ci][kk] (co=128,ci=12,kk=9) -> dst[(kk*12+ci)*128+co]  (conv1 f32 path)
__global__ void k_wprep(const float* __restrict__ src, float* __restrict__ dst, int L, int Cin) {
  int total = L * 128 * Cin * 9;
  for (int idx = blockIdx.x*blockDim.x + threadIdx.x; idx < total; idx += gridDim.x*blockDim.x) {
    int kk = idx % 9; int t2 = idx / 9;
    int ci = t2 % Cin; t2 /= Cin;
    int co = t2 % 128; int l  = t2 / 128;
    dst[((size_t)(l*9 + kk)*Cin + ci)*128 + co] = src[idx];
  }
}

// src[l][co][ci][kk] (128x128x9) -> dst f16 [(l*128+co)*1152 + kk*128 + ci]
__global__ void k_wprep16(const float* __restrict__ src, __half* __restrict__ dst, int L) {
  int total = L * 128 * 128 * 9;
  for (int idx = blockIdx.x*blockDim.x + threadIdx.x; idx < total; idx += gridDim.x*blockDim.x) {
    int kk = idx % 9; int t2 = idx / 9;
    int ci = t2 % 128; t2 /= 128;
    int co = t2 % 128; int l  = t2 / 128;
    dst[((size_t)(l*128 + co))*1152 + kk*128 + ci] = __float2half(src[idx]);
  }
}

// W f32 [K][N] -> WT f16 [N][K]
__global__ void k_wt16(const float* __restrict__ W, __half* __restrict__ WT, int K, int N) {
  int total = K * N;
  for (int idx = blockIdx.x*blockDim.x + threadIdx.x; idx < total; idx += gridDim.x*blockDim.x) {
    int k = idx / N, n = idx % N;
    WT[(size_t)n*K + k] = __float2half(W[idx]);
  }
}

// One layer's qkv/proj/fc1/fc2 f32 -> transposed f16 into wTt.
// q columns (n<512) of Wq and qkv bias are pre-scaled by hd^-0.5 = 0.125.
__global__ void k_wt16x4(const float* __restrict__ Wq, const float* __restrict__ Wp,
                         const float* __restrict__ W1, const float* __restrict__ W2,
                         const float* __restrict__ bq,
                         __half* __restrict__ wTt, float* __restrict__ biasbuf) {
  int gid0 = blockIdx.x*blockDim.x + threadIdx.x;
  if (gid0 < 1536) biasbuf[gid0] = bq[gid0] * (gid0 < 512 ? 0.125f : 1.f);
  const int TOT = 786432 + 3*262144;
  for (int idx = gid0; idx < TOT; idx += gridDim.x*blockDim.x) {
    if (idx < 786432) {
      int k = idx / 1536, n = idx % 1536;
      float v = Wq[idx] * (n < 512 ? 0.125f : 1.f);
      wTt[T_QKV + (size_t)n*512 + k] = __float2half(v);
    } else {
      int r0 = idx - 786432;
      int s = r0 / 262144, r = r0 % 262144;
      int k = r / 512, n = r % 512;
      const float* W = (s == 0) ? Wp : (s == 1) ? W1 : W2;
      wTt[T_PRJ + s*262144 + (size_t)n*512 + k] = __float2half(W[r]);
    }
  }
}

// ---------------- encode + conv1 (one-hot lookup), output f16 act ----------------
__global__ __launch_bounds__(256) void k_conv1(const int* __restrict__ xin,
    const float* __restrict__ wT1, const float* __restrict__ b1,
    __half* __restrict__ out) {
  __shared__ int s_w[64], s_b[64];
  int b = blockIdx.x, t = threadIdx.x;
  if (t < 64) { s_w[t] = xin[b*128 + t]; s_b[t] = xin[b*128 + 64 + t]; }
  __syncthreads();
  int p = t >> 2, i = t & 3;
  int y = p >> 3, x = p & 7;
  float acc[32];
  #pragma unroll
  for (int j = 0; j < 32; ++j) acc[j] = b1[i*32 + j];
  #pragma unroll
  for (int kk = 0; kk < 9; ++kk) {
    int ny = y + kk/3 - 1, nx = x + kk%3 - 1;
    if (ny < 0 || ny > 7 || nx < 0 || nx > 7) continue;
    int np = ny*8 + nx;
    int wp = s_w[np], bp = s_b[np];
    if (wp >= 1 && wp <= 6) {
      const float* w = &wT1[(size_t)(kk*12 + (wp-1))*128 + i*32];
      #pragma unroll
      for (int j = 0; j < 32; ++j) acc[j] += w[j];
    }
    if (bp >= 1 && bp <= 6) {
      const float* w = &wT1[(size_t)(kk*12 + 6 + (bp-1))*128 + i*32];
      #pragma unroll
      for (int j = 0; j < 32; ++j) acc[j] += w[j];
    }
  }
  __half* o = &out[((size_t)b*64 + p)*128 + i*32];
  #pragma unroll
  for (int j = 0; j < 16; ++j)
    *(__half2*)&o[j*2] = __floats2half2_rn(acc[j*2], acc[j*2+1]);
}

// ---------------- MFMA residual 3x3 conv + fused BN stats ----------------
#define IMG_W 136

__global__ __launch_bounds__(256) void k_conv_mfma(const __half* __restrict__ in,
    const __half* __restrict__ wT /* [128][1152] f16 */, const float* __restrict__ bias,
    const float* __restrict__ stats_in, const float* __restrict__ g,
    const float* __restrict__ bb, int use_bn, __half* __restrict__ out,
    float* __restrict__ stats_out) {
  __shared__ __align__(16) _Float16 s_img[2*65*IMG_W];  // 35,360 B (row 64 = zeros)
  __shared__ __align__(16) _Float16 s_B[2][4096];       // 2 x [128][32] linear, 16 KB
  __shared__ float s_sum[128], s_sq[128];               // 1 KB
  __shared__ float s_bnp[256];                          // 1 KB
  int b2 = blockIdx.x, t = threadIdx.x;
  int w = t >> 6, lane = t & 63;

  auto issueB = [&](int win, int buf) {
    #pragma unroll
    for (int i = 0; i < 2; ++i) {
      int rbase = (w*2 + i)*16;
      const __half* g2 = &wT[(size_t)(rbase + (lane>>2))*1152 + win*32 + (lane&3)*8];
      gll16(g2, &s_B[buf][rbase*32]);
    }
  };
  issueB(0, 0);

  if (use_bn && t < 128) {
    const float invN = 1.f / (float)NPOSR;
    float m = stats_in[t] * invN;
    float vv = stats_in[128+t] * invN - m*m;
    float sc = g[t] * rsqrtf(vv + 1e-5f);
    s_bnp[t] = sc;
    s_bnp[128+t] = bb[t] - m*sc;
  }
  __syncthreads();

  for (int idx4 = t; idx4 < 4096; idx4 += 256) {
    int img = idx4 >> 11, rr = (idx4 >> 5) & 63, c4 = (idx4 & 31) * 4;
    const __half* src = &in[((size_t)(b2*2 + img)*64 + rr)*128 + c4];
    float4 vv4 = ld_half4(src);
    float v0 = vv4.x, v1 = vv4.y, v2 = vv4.z, v3 = vv4.w;
    if (use_bn) {
      v0 = s_bnp[c4+0]*v0 + s_bnp[128+c4+0];
      v1 = s_bnp[c4+1]*v1 + s_bnp[128+c4+1];
      v2 = s_bnp[c4+2]*v2 + s_bnp[128+c4+2];
      v3 = s_bnp[c4+3]*v3 + s_bnp[128+c4+3];
    }
    f16x4 h;
    h[0] = (_Float16)fmaxf(v0, 0.f); h[1] = (_Float16)fmaxf(v1, 0.f);
    h[2] = (_Float16)fmaxf(v2, 0.f); h[3] = (_Float16)fmaxf(v3, 0.f);
    *(f16x4*)&s_img[(img*65 + rr)*IMG_W + c4] = h;
  }
  {
    int img = t >> 7, c = t & 127;
    s_img[(img*65 + 64)*IMG_W + c] = (_Float16)0.f;
    if (t < 128) { s_sum[t] = 0.f; s_sq[t] = 0.f; }
  }
  int wm = (w >> 1)*64, wn = (w & 1)*64;
  int fr = lane & 15, fq = lane >> 4;
  int imgo[4], yy[4], xx_[4];
  #pragma unroll
  for (int mt = 0; mt < 4; ++mt) {
    int r = wm + mt*16 + fr;
    imgo[mt] = r >> 6; int p = r & 63; yy[mt] = p >> 3; xx_[mt] = p & 7;
  }
  f32x4 acc[4][4];
  #pragma unroll
  for (int mt = 0; mt < 4; ++mt)
    #pragma unroll
    for (int nt = 0; nt < 4; ++nt) acc[mt][nt] = vzero4();
  __syncthreads();   // image + weight window 0 ready

  #pragma unroll
  for (int kk = 0; kk < 9; ++kk) {
    int dy = kk/3 - 1, dx = kk%3 - 1;
    const _Float16* abase[4];
    #pragma unroll
    for (int mt = 0; mt < 4; ++mt) {
      int ny = yy[mt] + dy, nx = xx_[mt] + dx;
      int row = ((unsigned)ny < 8u && (unsigned)nx < 8u) ? (ny*8 + nx) : 64;
      abase[mt] = &s_img[(imgo[mt]*65 + row)*IMG_W];
    }
    #pragma unroll
    for (int q = 0; q < 4; ++q) {
      int win = kk*4 + q;
      int buf = win & 1;
      if (win + 1 < 36) issueB(win + 1, buf ^ 1);
      f16x8 af[4], bf[4];
      #pragma unroll
      for (int mt = 0; mt < 4; ++mt) af[mt] = *(const f16x8*)&abase[mt][q*32 + fq*8];
      #pragma unroll
      for (int nt = 0; nt < 4; ++nt) bf[nt] = *(const f16x8*)&s_B[buf][(wn + nt*16 + fr)*32 + fq*8];
      #pragma unroll
      for (int mt = 0; mt < 4; ++mt)
        #pragma unroll
        for (int nt = 0; nt < 4; ++nt)
          acc[mt][nt] = __builtin_amdgcn_mfma_f32_16x16x32_f16(af[mt], bf[nt], acc[mt][nt], 0, 0, 0);
      __syncthreads();
    }
  }
  #pragma unroll
  for (int nt = 0; nt < 4; ++nt) {
    int col = wn + nt*16 + fr;
    float bv = bias[col];
    float s = 0.f, q = 0.f;
    #pragma unroll
    for (int mt = 0; mt < 4; ++mt) {
      int rbase = wm + mt*16 + fq*4;
      #pragma unroll
      for (int j = 0; j < 4; ++j) {
        int r = rbase + j;
        int img = r >> 6, p = r & 63;
        float v = acc[mt][nt][j] + bv;
        s += v; q += v*v;
        out[((size_t)(b2*2 + img)*64 + p)*128 + col] = __float2half(v);
      }
    }
    s += __shfl_xor(s, 16); s += __shfl_xor(s, 32);
    q += __shfl_xor(q, 16); q += __shfl_xor(q, 32);
    if (fq == 0) { atomicAdd(&s_sum[col], s); atomicAdd(&s_sq[col], q); }
  }
  __syncthreads();
  if (t < 128) {
    atomicAdd(&stats_out[t], s_sum[t]);
    atomicAdd(&stats_out[128 + t], s_sq[t]);
  }
}

// ---------------- t = window_partition(act + bn2(z1h)) + pos, in-place per image (f16) ----------------
__global__ __launch_bounds__(256) void k_make_t(__half* __restrict__ act,
    const __half* __restrict__ z1h, const float* __restrict__ stats_in,
    const float* __restrict__ g, const float* __restrict__ bb,
    const float* __restrict__ pos) {
  __shared__ float s_t[8192];
  __shared__ float s_bnp[256];
  int b = blockIdx.x, t = threadIdx.x;
  if (t < 128) {
    const float invN = 1.f / (float)NPOSR;
    float m = stats_in[t] * invN;
    float vv = stats_in[128+t] * invN - m*m;
    float sc = g[t] * rsqrtf(vv + 1e-5f);
    s_bnp[t] = sc;
    s_bnp[128+t] = bb[t] - m*sc;
  }
  __syncthreads();
  for (int idx4 = t; idx4 < 2048; idx4 += 256) {
    int n = idx4 >> 7, d4 = idx4 & 127;
    int d = d4*4, c = d & 127, q = d >> 7;
    int y = ((n>>2)<<1) + (q>>1), xx = ((n&3)<<1) + (q&1);
    size_t sp = ((size_t)b*64 + y*8 + xx)*128 + c;
    float4 a  = ld_half4(&act[sp]);
    float4 z  = ld_half4(&z1h[sp]);
    float4 sc = *(const float4*)&s_bnp[c];
    float4 sh = *(const float4*)&s_bnp[128+c];
    float4 pe = *(const float4*)&pos[n*512 + d];
    float4 o;
    o.x = a.x + sc.x*z.x + sh.x + pe.x;
    o.y = a.y + sc.y*z.y + sh.y + pe.y;
    o.z = a.z + sc.z*z.z + sh.z + pe.z;
    o.w = a.w + sc.w*z.w + sh.w + pe.w;
    *(float4*)&s_t[n*512 + d] = o;
  }
  __syncthreads();
  for (int idx8 = t; idx8 < 1024; idx8 += 256) {
    float4 v0 = *(float4*)&s_t[idx8*8];
    float4 v1 = *(float4*)&s_t[idx8*8 + 4];
    __half* o = &act[(size_t)b*8192 + idx8*8];
    st_half4(o, v0);
    st_half4(o + 4, v1);
  }
}

// ---------------- windowed attention from qkvbuf (1 image per block) ----------------
#define QS 1544   // padded row stride (halfs), 16B-aligned rows

__global__ __launch_bounds__(256) void k_attn16(const __half* __restrict__ qkvbuf,
    __half* __restrict__ attnout) {
  __shared__ __align__(16) _Float16 s_qkv[16][QS];   // 49,408 B
  __shared__ float S[8][16][17];                     //  8,704 B
  int img = blockIdx.x, t = threadIdx.x;
  const __half* src = qkvbuf + (size_t)img*16*1536;
  #pragma unroll
  for (int i = 0; i < 12; ++i) {
    int lin = t + i*256;
    int row = lin / 192, c8 = lin % 192;
    *(f16x8*)&s_qkv[row][c8*8] = *(const f16x8*)&src[(size_t)row*1536 + c8*8];
  }
  __syncthreads();
  {
    int h = t >> 5, qi = (t >> 1) & 15, ko = (t & 1) * 8;
    int rot = t & 31;
    float acc[8];
    #pragma unroll
    for (int k = 0; k < 8; ++k) acc[k] = 0.f;
    const __half2* qr = (const __half2*)&s_qkv[qi][h*64];
    for (int i2 = 0; i2 < 32; ++i2) {
      int d2 = (i2 + rot) & 31;
      float2 q2 = __half22float2(qr[d2]);
      #pragma unroll
      for (int k = 0; k < 8; ++k) {
        float2 k2 = __half22float2(*(const __half2*)&s_qkv[ko + k][512 + h*64 + d2*2]);
        acc[k] += q2.x*k2.x + q2.y*k2.y;
      }
    }
    #pragma unroll
    for (int k = 0; k < 8; ++k) S[h][qi][ko + k] = acc[k];
  }
  __syncthreads();
  if (t < 128) {
    int h = t >> 4, qi = t & 15;
    float* Sr = S[h][qi];
    float mx = -1e30f;
    #pragma unroll
    for (int ki = 0; ki < 16; ++ki) mx = fmaxf(mx, Sr[ki]);
    float sm = 0.f; float e[16];
    #pragma unroll
    for (int ki = 0; ki < 16; ++ki) { e[ki] = expf(Sr[ki] - mx); sm += e[ki]; }
    float inv = 1.f / sm;
    #pragma unroll
    for (int ki = 0; ki < 16; ++ki) Sr[ki] = e[ki]*inv;
  }
  __syncthreads();
  {
    int qi = t >> 4, rem = t & 15;
    int h = rem >> 1, dhb = (rem & 1) * 32;
    int rot = (t >> 2) & 15;
    float P[16];
    #pragma unroll
    for (int k = 0; k < 16; ++k) P[k] = S[h][qi][(k + rot) & 15];
    __half* orow = attnout + ((size_t)img*16 + qi)*512 + h*64 + dhb;
    #pragma unroll
    for (int j = 0; j < 16; ++j) {
      int dh = dhb + 2*j;
      float a0 = 0.f, a1 = 0.f;
      #pragma unroll
      for (int kk2 = 0; kk2 < 16; ++kk2) {
        int ki = (kk2 + rot) & 15;
        float2 v2 = __half22float2(*(const __half2*)&s_qkv[ki][1024 + h*64 + dh]);
        a0 += P[kk2]*v2.x; a1 += P[kk2]*v2.y;
      }
      *(__half2*)&orow[2*j] = __floats2half2_rn(a0, a1);
    }
  }
}

// ---------------- generic MFMA GEMM: C = act(A@B + bias) ----------------
template<int MTI, int NTI, int A16, int B16, int RELU, int OUT16>
__global__ __launch_bounds__(256) void k_mgemm(const void* __restrict__ Ap,
    const void* __restrict__ Bp, const float* __restrict__ bias,
    void* __restrict__ Cp, int M, int N, int K) {
  constexpr int BM = MTI*32;
  constexpr int BN = NTI*32;
  __shared__ __align__(16) _Float16 sA[2][BM*32];
  __shared__ __align__(16) _Float16 sB[2][BN*32];
  int t = threadIdx.x;
  int bm = blockIdx.x * BM, bn = blockIdx.y * BN;
  int w = t >> 6, lane = t & 63;
  int wm = (w >> 1) * (MTI*16), wn = (w & 1) * (NTI*16);
  int fr = lane & 15, fq = lane >> 4;

  auto stageA = [&](int k0, int buf) {
    if (A16) {
      const __half* A = (const __half*)Ap;
      constexpr int NI = MTI/2;
      #pragma unroll
      for (int i = 0; i < NI; ++i) {
        int rbase = (w*NI + i)*16;
        gll16(&A[(size_t)(bm + rbase + (lane>>2))*K + k0 + (lane&3)*8],
              &sA[buf][rbase*32]);
      }
    } else {
      const float* A = (const float*)Ap;
      if (MTI == 4) {
        int srow = t >> 1, skh = (t & 1) * 16;
        const float4* src = (const float4*)&A[(size_t)(bm + srow)*K + k0 + skh];
        float4 v0 = src[0], v1 = src[1], v2 = src[2], v3 = src[3];
        f16x8 h0, h1;
        h0[0]=(_Float16)v0.x; h0[1]=(_Float16)v0.y; h0[2]=(_Float16)v0.z; h0[3]=(_Float16)v0.w;
        h0[4]=(_Float16)v1.x; h0[5]=(_Float16)v1.y; h0[6]=(_Float16)v1.z; h0[7]=(_Float16)v1.w;
        h1[0]=(_Float16)v2.x; h1[1]=(_Float16)v2.y; h1[2]=(_Float16)v2.z; h1[3]=(_Float16)v2.w;
        h1[4]=(_Float16)v3.x; h1[5]=(_Float16)v3.y; h1[6]=(_Float16)v3.z; h1[7]=(_Float16)v3.w;
        *(f16x8*)&sA[buf][srow*32 + skh]     = h0;
        *(f16x8*)&sA[buf][srow*32 + skh + 8] = h1;
      } else {
        int srow = t >> 2, g8 = (t & 3) * 8;
        const float4* src = (const float4*)&A[(size_t)(bm + srow)*K + k0 + g8];
        float4 v0 = src[0], v1 = src[1];
        f16x8 h0;
        h0[0]=(_Float16)v0.x; h0[1]=(_Float16)v0.y; h0[2]=(_Float16)v0.z; h0[3]=(_Float16)v0.w;
        h0[4]=(_Float16)v1.x; h0[5]=(_Float16)v1.y; h0[6]=(_Float16)v1.z; h0[7]=(_Float16)v1.w;
        *(f16x8*)&sA[buf][srow*32 + g8] = h0;
      }
    }
  };
  auto stageB = [&](int k0, int buf) {
    if (B16) {
      const __half* BT = (const __half*)Bp;
      constexpr int NBI = NTI/2;
      #pragma unroll
      for (int i = 0; i < NBI; ++i) {
        int rbase = (w*NBI + i)*16;
        gll16(&BT[(size_t)(bn + rbase + (lane>>2))*K + k0 + (lane&3)*8],
              &sB[buf][rbase*32]);
      }
    } else {
      const float* B = (const float*)Bp;
      int kr = t >> 3, n0 = (t & 7) * 16;
      #pragma unroll
      for (int g = 0; g < 4; ++g) {
        float4 v = *(const float4*)&B[(size_t)(k0 + kr)*N + bn + n0 + g*4];
        sB[buf][(n0+g*4+0)*32 + kr] = (_Float16)v.x;
        sB[buf][(n0+g*4+1)*32 + kr] = (_Float16)v.y;
        sB[buf][(n0+g*4+2)*32 + kr] = (_Float16)v.z;
        sB[buf][(n0+g*4+3)*32 + kr] = (_Float16)v.w;
      }
    }
  };

  f32x4 acc[MTI][NTI];
  #pragma unroll
  for (int mt = 0; mt < MTI; ++mt)
    #pragma unroll
    for (int nt = 0; nt < NTI; ++nt) acc[mt][nt] = vzero4();

  stageA(0, 0); stageB(0, 0);
  __syncthreads();
  int KW = K >> 5;
  for (int kw = 0; kw < KW; ++kw) {
    int buf = kw & 1;
    if (kw + 1 < KW) { stageA((kw+1)*32, buf ^ 1); stageB((kw+1)*32, buf ^ 1); }
    f16x8 af[MTI], bf[NTI];
    #pragma unroll
    for (int mt = 0; mt < MTI; ++mt) af[mt] = *(const f16x8*)&sA[buf][(wm + mt*16 + fr)*32 + fq*8];
    #pragma unroll
    for (int nt = 0; nt < NTI; ++nt) bf[nt] = *(const f16x8*)&sB[buf][(wn + nt*16 + fr)*32 + fq*8];
    #pragma unroll
    for (int mt = 0; mt < MTI; ++mt)
      #pragma unroll
      for (int nt = 0; nt < NTI; ++nt)
        acc[mt][nt] = __builtin_amdgcn_mfma_f32_16x16x32_f16(af[mt], bf[nt], acc[mt][nt], 0, 0, 0);
    __syncthreads();
  }
  #pragma unroll
  for (int mt = 0; mt < MTI; ++mt)
    #pragma unroll
    for (int nt = 0; nt < NTI; ++nt) {
      int col = bn + wn + nt*16 + fr;
      float bv = bias[col];
      #pragma unroll
      for (int j = 0; j < 4; ++j) {
        int row = bm + wm + mt*16 + fq*4 + j;
        float v = acc[mt][nt][j] + bv;
        if (RELU) v = fmaxf(v, 0.f);
        if (OUT16) ((__half*)Cp)[(size_t)row*N + col] = __float2half(v);
        else       ((float*)Cp)[(size_t)row*N + col] = v;
      }
    }
}

// ---------------- t2 = t(f16) + LN(gemm_out): writes f16 t2 ----------------
__global__ __launch_bounds__(256) void k_lnres(const __half* __restrict__ pout,
    const __half* __restrict__ tact, __half* __restrict__ t2h) {
  int t = threadIdx.x;
  int tok = blockIdx.x*4 + (t >> 6);
  int lane = t & 63;
  f16x8 hv = *(const f16x8*)&pout[(size_t)tok*512 + lane*8];
  float v[8]; float s1 = 0.f, s2 = 0.f;
  #pragma unroll
  for (int j = 0; j < 8; ++j) { v[j] = (float)hv[j]; s1 += v[j]; s2 += v[j]*v[j]; }
  #pragma unroll
  for (int m = 32; m >= 1; m >>= 1) { s1 += __shfl_xor(s1, m); s2 += __shfl_xor(s2, m); }
  float mean = s1 * (1.f/512.f);
  float var  = s2 * (1.f/512.f) - mean*mean;
  float rs = rsqrtf(var + 1e-6f);
  f16x8 av = *(const f16x8*)&tact[(size_t)tok*512 + lane*8];
  f16x8 o16;
  #pragma unroll
  for (int j = 0; j < 8; ++j) {
    float t2 = (float)av[j] + (v[j] - mean)*rs;
    o16[j] = (_Float16)t2;
  }
  *(f16x8*)&t2h[(size_t)tok*512 + lane*8] = o16;
}

// ---------------- t2(f16) + LN(fc2out), window_reverse to spatial (f16), per image ----------------
__global__ __launch_bounds__(256) void k_lnres2(const __half* __restrict__ fout,
    const __half* __restrict__ t2h, __half* __restrict__ actimg) {
  __shared__ float s_t2[8192];
  int bimg = blockIdx.x, t = threadIdx.x;
  int lane = t & 63;
  for (int tg = 0; tg < 4; ++tg) {
    int n = tg*4 + (t >> 6);
    size_t row = (size_t)bimg*16 + n;
    f16x8 hv = *(const f16x8*)&fout[row*512 + lane*8];
    float v[8]; float s1 = 0.f, s2 = 0.f;
    #pragma unroll
    for (int j = 0; j < 8; ++j) { v[j] = (float)hv[j]; s1 += v[j]; s2 += v[j]*v[j]; }
    #pragma unroll
    for (int m = 32; m >= 1; m >>= 1) { s1 += __shfl_xor(s1, m); s2 += __shfl_xor(s2, m); }
    float mean = s1 * (1.f/512.f);
    float var  = s2 * (1.f/512.f) - mean*mean;
    float rs = rsqrtf(var + 1e-6f);
    f16x8 tv = *(const f16x8*)&t2h[row*512 + lane*8];
    #pragma unroll
    for (int j = 0; j < 8; ++j)
      s_t2[n*512 + lane*8 + j] = (float)tv[j] + (v[j] - mean)*rs;
  }
  __syncthreads();
  for (int idx = t; idx < 1024; idx += 256) {
    int p = idx >> 4, c = (idx & 15)*8;
    int y = p >> 3, x = p & 7;
    int n = (y >> 1)*4 + (x >> 1);
    int d = ((y & 1)*2 + (x & 1))*128 + c;
    float4 v0 = *(float4*)&s_t2[n*512 + d];
    float4 v1 = *(float4*)&s_t2[n*512 + d + 4];
    __half* o = &actimg[(size_t)bimg*8192 + p*128 + c];
    st_half4(o, v0);
    st_half4(o + 4, v1);
  }
}

// ---------------- row softmax (640) ----------------
__global__ __launch_bounds__(256) void k_softmax(const float* __restrict__ logits, float* __restrict__ out) {
  int b = blockIdx.x, t = threadIdx.x;
  __shared__ float red[256];
  float m = -1e30f;
  for (int j = t; j < 640; j += 256) m = fmaxf(m, logits[(size_t)b*640 + j]);
  red[t] = m; __syncthreads();
  for (int s = 128; s > 0; s >>= 1) { if (t < s) red[t] = fmaxf(red[t], red[t+s]); __syncthreads(); }
  m = red[0]; __syncthreads();
  float sum = 0.f;
  for (int j = t; j < 640; j += 256) sum += expf(logits[(size_t)b*640 + j] - m);
  red[t] = sum; __syncthreads();
  for (int s = 128; s > 0; s >>= 1) { if (t < s) red[t] += red[t+s]; __syncthreads(); }
  float inv = 1.f / red[0];
  for (int j = t; j < 640; j += 256) out[(size_t)b*640 + j] = expf(logits[(size_t)b*640 + j] - m) * inv;
}

// ---------------- host ----------------
extern "C" void kernel_launch(void* const* d_in, const int* in_sizes, int n_in,
                              void* d_out, int out_size, void* d_ws, size_t ws_size,
                              hipStream_t stream) {
  (void)in_sizes; (void)n_in;
  float* out = (float*)d_out;
  if (ws_size < (size_t)WS_NEED_FLOATS * 4) {
    k_sentinel<<<2048, 256, 0, stream>>>(out, out_size, (float)(ws_size >> 20));
    return;
  }

  const int*   x       = (const int*)d_in[0];
  const float* pos     = (const float*)d_in[1];
  const float* conv1_w = (const float*)d_in[2];
  const float* conv1_b = (const float*)d_in[3];
  const float* rb1_w   = (const float*)d_in[4];
  const float* rb1_b   = (const float*)d_in[5];
  const float* bn1_g   = (const float*)d_in[6];
  const float* bn1_b   = (const float*)d_in[7];
  const float* rb2_w   = (const float*)d_in[8];
  const float* rb2_b   = (const float*)d_in[9];
  const float* bn2_g   = (const float*)d_in[10];
  const float* bn2_b   = (const float*)d_in[11];
  const float* qkv_w   = (const float*)d_in[12];
  const float* qkv_b   = (const float*)d_in[13];
  const float* proj_w  = (const float*)d_in[14];
  const float* proj_b  = (const float*)d_in[15];
  const float* fc1_w   = (const float*)d_in[16];
  const float* fc1_b   = (const float*)d_in[17];
  const float* fc2_w   = (const float*)d_in[18];
  const float* fc2_b   = (const float*)d_in[19];
  const float* lin1_w  = (const float*)d_in[20];
  const float* lin1_b  = (const float*)d_in[21];
  const float* lin2_w  = (const float*)d_in[22];
  const float* lin2_b  = (const float*)d_in[23];

  float*  ws    = (float*)d_ws;
  __half* act16 = (__half*)(ws + OFF_ACT);
  __half* big2h = (__half*)(ws + OFF_BIG2);
  float*  wT1   = ws + OFF_WT1;
  __half* wTa16 = (__half*)(ws + OFF_WTA);
  __half* wTb16 = (__half*)(ws + OFF_WTB);
  __half* wTt   = (__half*)(ws + OFF_WTT);
  float*  stats20 = ws + OFF_STATS;     // 20 x 256
  float*  biasbuf = ws + OFF_BIAS;

  __half* z1h     = big2h;
  __half* qkvbuf  = big2h + H_QKVB;
  __half* attnout = big2h + H_ATT;
  __half* projout = big2h + H_QKVB;     // overlays qkvbuf (dead after attn)
  __half* t2h     = big2h + H_T2H;      // overlays qkvbuf tail (dead after attn)
  __half* h1      = attnout;            // attnout dead after proj gemm
  __half* fc2out  = projout;            // projout dead after lnres
  __half* qkvT    = wTt + T_QKV;
  __half* projT   = wTt + T_PRJ;
  __half* fc1T    = wTt + T_F1;
  __half* fc2T    = wTt + T_F2;
  __half* L1h     = big2h;
  float*  logits  = (float*)(big2h + H_LOG);
  __half* lin2T   = wTt;

  k_zero<<<20, 256, 0, stream>>>(stats20);
  k_wprep<<<64, 256, 0, stream>>>(conv1_w, wT1, 1, 12);
  k_wprep16<<<2048, 256, 0, stream>>>(rb1_w, wTa16, 10);
  k_wprep16<<<2048, 256, 0, stream>>>(rb2_w, wTb16, 10);
  k_conv1<<<NBATCH, 256, 0, stream>>>(x, wT1, conv1_b, act16);

  for (int l = 0; l < 10; ++l) {
    float* statsA = stats20 + (size_t)(2*l)*256;
    float* statsB = stats20 + (size_t)(2*l + 1)*256;
    k_conv_mfma<<<NBATCH/2, 256, 0, stream>>>(act16, wTa16 + (size_t)l*147456,
        rb1_b + l*128, (const float*)nullptr, (const float*)nullptr,
        (const float*)nullptr, 0, z1h, statsA);
    k_conv_mfma<<<NBATCH/2, 256, 0, stream>>>(z1h, wTb16 + (size_t)l*147456,
        rb2_b + l*128, statsA, bn1_g + l*128, bn1_b + l*128, 1, z1h, statsB);
    k_make_t<<<NBATCH, 256, 0, stream>>>(act16, z1h, statsB, bn2_g + l*128,
        bn2_b + l*128, pos);   // z1h dead after this

    k_wt16x4<<<2048, 256, 0, stream>>>(qkv_w + (size_t)l*786432,
        proj_w + (size_t)l*262144, fc1_w + (size_t)l*262144, fc2_w + (size_t)l*262144,
        qkv_b + l*1536, wTt, biasbuf);

    for (int ch = 0; ch < NBATCH/CH; ++ch) {
      __half* tchunk = act16 + (size_t)ch*CH*8192;
      // qkv = t @ Wqkv + b (q pre-scaled); A16 path with global_load_lds
      k_mgemm<4,4,1,1,0,1><<<dim3(CHT/128, 12), 256, 0, stream>>>(tchunk, qkvT,
          biasbuf, qkvbuf, CHT, 1536, 512);
      k_attn16<<<CH, 256, 0, stream>>>(qkvbuf, attnout);
      k_mgemm<4,4,1,1,0,1><<<dim3(CHT/128, 4), 256, 0, stream>>>(attnout, projT,
          proj_b + l*512, projout, CHT, 512, 512);
      k_lnres<<<CHT/4, 256, 0, stream>>>(projout, tchunk, t2h);
      k_mgemm<4,4,1,1,1,1><<<dim3(CHT/128, 4), 256, 0, stream>>>(t2h, fc1T,
          fc1_b + l*512, h1, CHT, 512, 512);
      k_mgemm<4,4,1,1,0,1><<<dim3(CHT/128, 4), 256, 0, stream>>>(h1, fc2T,
          fc2_b + l*512, fc2out, CHT, 512, 512);
      k_lnres2<<<CH, 256, 0, stream>>>(fc2out, t2h, tchunk);
    }
  }
  k_mgemm<2,4,1,0,1,1><<<dim3(4096/64, 8), 256, 0, stream>>>(act16, lin1_w, lin1_b, L1h,
      4096, 1024, 8192);
  k_wt16<<<512, 256, 0, stream>>>(lin2_w, lin2T, 1024, 640);
  k_mgemm<2,4,1,1,0,0><<<dim3(4096/64, 5), 256, 0, stream>>>(L1h, lin2T, lin2_b, logits,
      4096, 640, 1024);
  k_softmax<<<NBATCH, 256, 0, stream>>>(logits, out);
}